// Round 13
// baseline (423.597 us; speedup 1.0000x reference)
//
#include <hip/hip_runtime.h>

// Per-token asymmetric fake-quant (8-bit) over last dim (4096).
// x: fp32 [B=4, S=4096, D=4096]. One 256-thread block per row; each thread
// holds 16 elements in registers (4x float4) so the row is read from HBM once.

#define QMAX_F 255.0f
#define CLIPMIN_F 1e-5f
#define CLIPMAX_F 10000.0f

__global__ __launch_bounds__(256) void actquant_kernel(
    const float* __restrict__ x, float* __restrict__ out) {
    const int t = threadIdx.x;
    const long long base = (long long)blockIdx.x * 4096;
    const float4* __restrict__ xin = reinterpret_cast<const float4*>(x + base);
    float4* __restrict__ xout = reinterpret_cast<float4*>(out + base);

    // Load the whole row into registers: 4 chunks of 256 lanes x float4.
    float4 v[4];
#pragma unroll
    for (int k = 0; k < 4; ++k) v[k] = xin[t + k * 256];

    // Per-thread min/max over 16 values.
    float mn = v[0].x, mx = v[0].x;
#pragma unroll
    for (int k = 0; k < 4; ++k) {
        mn = fminf(mn, fminf(fminf(v[k].x, v[k].y), fminf(v[k].z, v[k].w)));
        mx = fmaxf(mx, fmaxf(fmaxf(v[k].x, v[k].y), fmaxf(v[k].z, v[k].w)));
    }

    // Wave64 butterfly reduction.
#pragma unroll
    for (int off = 32; off > 0; off >>= 1) {
        mn = fminf(mn, __shfl_xor(mn, off));
        mx = fmaxf(mx, __shfl_xor(mx, off));
    }

    // Cross-wave combine (4 waves/block).
    __shared__ float smn[4], smx[4];
    const int wave = t >> 6;
    if ((t & 63) == 0) { smn[wave] = mn; smx[wave] = mx; }
    __syncthreads();
    mn = fminf(fminf(smn[0], smn[1]), fminf(smn[2], smn[3]));
    mx = fmaxf(fmaxf(smx[0], smx[1]), fmaxf(smx[2], smx[3]));

    // scale = clip((max-min)/255, 1e-5, 1e4); zp = clip(-min/scale, -1e4, 1e4)
    const float scale = fminf(fmaxf((mx - mn) / QMAX_F, CLIPMIN_F), CLIPMAX_F);
    const float zp = fminf(fmaxf(-mn / scale, -CLIPMAX_F), CLIPMAX_F);

    // Fake quant-dequant from registers; rintf == round-half-even == jnp.round.
    // Plain IEEE division (no fast-math) so rounding boundaries match XLA.
#pragma unroll
    for (int k = 0; k < 4; ++k) {
        float4 o;
        const float* pv = &v[k].x;
        float* po = &o.x;
#pragma unroll
        for (int j = 0; j < 4; ++j) {
            float xi = rintf(pv[j] / scale) + zp;
            xi = fminf(fmaxf(xi, 0.0f), QMAX_F);
            po[j] = (xi - zp) * scale;
        }
        xout[t + k * 256] = o;
    }
}

extern "C" void kernel_launch(void* const* d_in, const int* in_sizes, int n_in,
                              void* d_out, int out_size, void* d_ws, size_t ws_size,
                              hipStream_t stream) {
    const float* x = (const float*)d_in[0];
    float* out = (float*)d_out;
    const int rows = in_sizes[0] / 4096;  // 16384
    actquant_kernel<<<rows, 256, 0, stream>>>(x, out);
}